// Round 9
// baseline (65.402 us; speedup 1.0000x reference)
//
#include <hip/hip_runtime.h>

#define HH 512
#define WW 512
#define CC 3
#define WGB 8                  // 64-row bands per plane
#define NWG (WGB * CC * 32)    // 768
#define NXCD 8

// d_ws layout: float blocks[32][4][4] (2048 B), unsigned counter @2048

__global__ __launch_bounds__(256) void lap_block_sum_kernel(
    const float* __restrict__ gt, const float* __restrict__ sp,
    float* __restrict__ blocks, unsigned* __restrict__ counter,
    float* __restrict__ out)
{
    __shared__ float ldsr[16][WW];   // P1 boundaries in slots 0-7, P2 in 8-15
    __shared__ float red[4][4];
    __shared__ int lastFlag;
    __shared__ float bmax[32];

    const int orig = blockIdx.x;
    const int lin  = (orig & (NXCD - 1)) * (NWG / NXCD) + (orig >> 3);
    const int wgband = lin & (WGB - 1);
    const int plane  = lin >> 3;          // = b*CC + c
    const int c = plane % CC;

    const int t = threadIdx.x;
    const int wv = t >> 6, lane = t & 63;

    const size_t poff = (size_t)plane * (size_t)(HH * WW);
    const float* __restrict__ gtp = gt + poff;
    const float* __restrict__ spp = sp + poff;

    const int start = wgband * 64;
    const int h1 = start + wv * 8;        // pass-1 rows [h1, h1+8)
    const int h2 = start + 32 + wv * 8;   // pass-2 rows [h2, h2+8)
    const int colA = 4 * lane;
    const int colB = 256 + 4 * lane;

#define LOADDIFF(HS, DA, DB) do {                                   \
    const float* gr_ = gtp + (size_t)(HS) * WW;                     \
    const float* sr_ = spp + (size_t)(HS) * WW;                     \
    float4 ga_ = *(const float4*)(gr_ + colA);                      \
    float4 gb_ = *(const float4*)(gr_ + colB);                      \
    float4 sa_ = *(const float4*)(sr_ + colA);                      \
    float4 sb_ = *(const float4*)(sr_ + colB);                      \
    DA[0]=ga_.x-sa_.x; DA[1]=ga_.y-sa_.y;                           \
    DA[2]=ga_.z-sa_.z; DA[3]=ga_.w-sa_.w;                           \
    DB[0]=gb_.x-sb_.x; DB[1]=gb_.y-sb_.y;                           \
    DB[2]=gb_.z-sb_.z; DB[3]=gb_.w-sb_.w;                           \
} while (0)

    // ---- pass 1: halo + 8 rows, publish boundaries ----
    float hA[4], hB[4];   // wv0: row start-1 (reflect); wv3: row start+32
    if (wv == 0 || wv == 3) {
        int hs = (wv == 0) ? (start == 0 ? 1 : start - 1) : (start + 32);
        LOADDIFF(hs, hA, hB);
    }

    float d1A[8][4], d1B[8][4];
    #pragma unroll
    for (int r = 0; r < 8; ++r) LOADDIFF(h1 + r, d1A[r], d1B[r]);

    *(float4*)&ldsr[2*wv  ][colA] = *(const float4*)&d1A[0][0];
    *(float4*)&ldsr[2*wv  ][colB] = *(const float4*)&d1B[0][0];
    *(float4*)&ldsr[2*wv+1][colA] = *(const float4*)&d1A[7][0];
    *(float4*)&ldsr[2*wv+1][colB] = *(const float4*)&d1B[7][0];
    __syncthreads();   // barrier 1 (drains P1 loads)

    float p1A[4], p1B[4], n1A[4], n1B[4];
    if (wv == 0) {
        #pragma unroll
        for (int i = 0; i < 4; ++i) { p1A[i]=hA[i]; p1B[i]=hB[i]; }
    } else {
        float4 a = *(const float4*)&ldsr[2*wv-1][colA];
        float4 q = *(const float4*)&ldsr[2*wv-1][colB];
        p1A[0]=a.x;p1A[1]=a.y;p1A[2]=a.z;p1A[3]=a.w;
        p1B[0]=q.x;p1B[1]=q.y;p1B[2]=q.z;p1B[3]=q.w;
    }
    if (wv == 3) {
        #pragma unroll
        for (int i = 0; i < 4; ++i) { n1A[i]=hA[i]; n1B[i]=hB[i]; }
    } else {
        float4 a = *(const float4*)&ldsr[2*wv+2][colA];
        float4 q = *(const float4*)&ldsr[2*wv+2][colB];
        n1A[0]=a.x;n1A[1]=a.y;n1A[2]=a.z;n1A[3]=a.w;
        n1B[0]=q.x;n1B[1]=q.y;n1B[2]=q.z;n1B[3]=q.w;
    }

    // ---- stencil machinery ----
    const int hzA0 = colA/384, hzA1 = (512+colA)/384, hzA2 = (1024+colA)/384;
    const int hzB0 = colB/384, hzB1 = (512+colB)/384, hzB2 = (1024+colB)/384;
    const int lm1 = (lane + 63) & 63, lp1 = (lane + 1) & 63;

    float acc0=0.f, acc1=0.f, acc2=0.f, acc3=0.f;

#define ROWSTEP(DDA,DDB,TA,TB,RM,BA,BB) do {                            \
    float csA0 = TA[0]+DDA[RM][0]+BA[0];                                \
    float csA1 = TA[1]+DDA[RM][1]+BA[1];                                \
    float csA2 = TA[2]+DDA[RM][2]+BA[2];                                \
    float csA3 = TA[3]+DDA[RM][3]+BA[3];                                \
    float csB0 = TB[0]+DDB[RM][0]+BB[0];                                \
    float csB1 = TB[1]+DDB[RM][1]+BB[1];                                \
    float csB2 = TB[2]+DDB[RM][2]+BB[2];                                \
    float csB3 = TB[3]+DDB[RM][3]+BB[3];                                \
    float sA3m = __shfl(csA3, lm1), sA0p = __shfl(csA0, lp1);           \
    float sB3m = __shfl(csB3, lm1), sB0p = __shfl(csB0, lp1);           \
    float xR = __shfl(csB0, 0),     xL = __shfl(csA3, 63);              \
    float lA = (lane==0)  ? csA1 : sA3m;  /* col -1 -> reflect col 1 */ \
    float rA = (lane==63) ? xR   : sA0p;  /* col 256 */                 \
    float lB = (lane==0)  ? xL   : sB3m;  /* col 255 */                 \
    float rB = (lane==63) ? csB2 : sB0p;  /* col 512 -> reflect 510 */  \
    float sA = fabsf(lA  +csA0+csA1 - 9.f*DDA[RM][0])                   \
             + fabsf(csA0+csA1+csA2 - 9.f*DDA[RM][1])                   \
             + fabsf(csA1+csA2+csA3 - 9.f*DDA[RM][2])                   \
             + fabsf(csA2+csA3+rA   - 9.f*DDA[RM][3]);                  \
    float sB = fabsf(lB  +csB0+csB1 - 9.f*DDB[RM][0])                   \
             + fabsf(csB0+csB1+csB2 - 9.f*DDB[RM][1])                   \
             + fabsf(csB1+csB2+csB3 - 9.f*DDB[RM][2])                   \
             + fabsf(csB2+csB3+rB   - 9.f*DDB[RM][3]);                  \
    int hzA = (m==0)?hzA0:((m==1)?hzA1:hzA2);                           \
    int hzB = (m==0)?hzB0:((m==1)?hzB1:hzB2);                           \
    acc0 += ((hzA==0)?sA:0.f) + ((hzB==0)?sB:0.f);                      \
    acc1 += ((hzA==1)?sA:0.f) + ((hzB==1)?sB:0.f);                      \
    acc2 += ((hzA==2)?sA:0.f) + ((hzB==2)?sB:0.f);                      \
    acc3 += ((hzA==3)?sA:0.f) + ((hzB==3)?sB:0.f);                      \
    m = (m==2)?0:(m+1);                                                 \
} while(0)

    // ---- pass-2 loads interleaved into pass-1 compute ----
    float d2A[8][4], d2B[8][4];
    float h3A[4], h3B[4];   // P2 bottom halo (wv3): row start+64, reflect at 512
    if (wv == 3) {
        int hs = (start + 64 > HH - 1) ? HH - 2 : start + 64;
        LOADDIFF(hs, h3A, h3B);
    }

    int m = (c * HH + h1) % 3;

    LOADDIFF(h2 + 0, d2A[0], d2B[0]);
    ROWSTEP(d1A,d1B, p1A,   p1B,   0, d1A[1], d1B[1]);
    LOADDIFF(h2 + 1, d2A[1], d2B[1]);
    ROWSTEP(d1A,d1B, d1A[0],d1B[0], 1, d1A[2], d1B[2]);
    LOADDIFF(h2 + 2, d2A[2], d2B[2]);
    ROWSTEP(d1A,d1B, d1A[1],d1B[1], 2, d1A[3], d1B[3]);
    LOADDIFF(h2 + 3, d2A[3], d2B[3]);
    ROWSTEP(d1A,d1B, d1A[2],d1B[2], 3, d1A[4], d1B[4]);
    LOADDIFF(h2 + 4, d2A[4], d2B[4]);
    ROWSTEP(d1A,d1B, d1A[3],d1B[3], 4, d1A[5], d1B[5]);
    LOADDIFF(h2 + 5, d2A[5], d2B[5]);
    ROWSTEP(d1A,d1B, d1A[4],d1B[4], 5, d1A[6], d1B[6]);
    LOADDIFF(h2 + 6, d2A[6], d2B[6]);
    ROWSTEP(d1A,d1B, d1A[5],d1B[5], 6, d1A[7], d1B[7]);
    LOADDIFF(h2 + 7, d2A[7], d2B[7]);
    ROWSTEP(d1A,d1B, d1A[6],d1B[6], 7, n1A,    n1B);

    // ---- pass 2: publish boundaries, compute ----
    *(float4*)&ldsr[8+2*wv  ][colA] = *(const float4*)&d2A[0][0];
    *(float4*)&ldsr[8+2*wv  ][colB] = *(const float4*)&d2B[0][0];
    *(float4*)&ldsr[8+2*wv+1][colA] = *(const float4*)&d2A[7][0];
    *(float4*)&ldsr[8+2*wv+1][colB] = *(const float4*)&d2B[7][0];
    __syncthreads();   // barrier 2 (P2 loads long since landed)

    float p2A[4], p2B[4], n2A[4], n2B[4];
    {
        // wv0's prev row (start+31) is P1 wv3's bottom boundary = slot 7
        const int ps = (wv == 0) ? 7 : (8 + 2*wv - 1);
        float4 a = *(const float4*)&ldsr[ps][colA];
        float4 q = *(const float4*)&ldsr[ps][colB];
        p2A[0]=a.x;p2A[1]=a.y;p2A[2]=a.z;p2A[3]=a.w;
        p2B[0]=q.x;p2B[1]=q.y;p2B[2]=q.z;p2B[3]=q.w;
    }
    if (wv == 3) {
        #pragma unroll
        for (int i = 0; i < 4; ++i) { n2A[i]=h3A[i]; n2B[i]=h3B[i]; }
    } else {
        float4 a = *(const float4*)&ldsr[8+2*wv+2][colA];
        float4 q = *(const float4*)&ldsr[8+2*wv+2][colB];
        n2A[0]=a.x;n2A[1]=a.y;n2A[2]=a.z;n2A[3]=a.w;
        n2B[0]=q.x;n2B[1]=q.y;n2B[2]=q.z;n2B[3]=q.w;
    }

    m = (c * HH + h2) % 3;
    ROWSTEP(d2A,d2B, p2A,   p2B,   0, d2A[1], d2B[1]);
    ROWSTEP(d2A,d2B, d2A[0],d2B[0], 1, d2A[2], d2B[2]);
    ROWSTEP(d2A,d2B, d2A[1],d2B[1], 2, d2A[3], d2B[3]);
    ROWSTEP(d2A,d2B, d2A[2],d2B[2], 3, d2A[4], d2B[4]);
    ROWSTEP(d2A,d2B, d2A[3],d2B[3], 4, d2A[5], d2B[5]);
    ROWSTEP(d2A,d2B, d2A[4],d2B[4], 5, d2A[6], d2B[6]);
    ROWSTEP(d2A,d2B, d2A[5],d2B[5], 6, d2A[7], d2B[7]);
    ROWSTEP(d2A,d2B, d2A[6],d2B[6], 7, n2A,    n2B);
#undef ROWSTEP
#undef LOADDIFF

    // ---- reduce across both passes ----
    #pragma unroll
    for (int off = 32; off > 0; off >>= 1) {
        acc0 += __shfl_xor(acc0, off);
        acc1 += __shfl_xor(acc1, off);
        acc2 += __shfl_xor(acc2, off);
        acc3 += __shfl_xor(acc3, off);
    }
    if (lane == 0) {
        red[wv][0] = acc0 * 0.0625f; red[wv][1] = acc1 * 0.0625f;
        red[wv][2] = acc2 * 0.0625f; red[wv][3] = acc3 * 0.0625f;
    }
    __syncthreads();

    const int v = (c * HH + start) / 384;   // uniform over the 64-row band
    const int b = plane / CC;
    if (t < 4) {
        float r = red[0][t] + red[1][t] + red[2][t] + red[3][t];
        atomicAdd(&blocks[(b * 4 + v) * 4 + t], r);   // device-coherent RMW
    }
    __syncthreads();   // barrier drains vmcnt -> atomics complete

    // ---- last workgroup finalizes (no threadfence: all data flowed via atomics) ----
    if (t == 0) {
        unsigned old = __hip_atomic_fetch_add(counter, 1u, __ATOMIC_ACQ_REL,
                                              __HIP_MEMORY_SCOPE_AGENT);
        lastFlag = (old == (unsigned)(NWG - 1));
    }
    __syncthreads();
    if (!lastFlag) return;

    // 512 entries = blocks[b][v][hz]; thread t handles entries t and t+256
    float x0 = __hip_atomic_load(&blocks[t], __ATOMIC_RELAXED,
                                 __HIP_MEMORY_SCOPE_AGENT);
    float x1 = __hip_atomic_load(&blocks[t + 256], __ATOMIC_RELAXED,
                                 __HIP_MEMORY_SCOPE_AGENT);
    // max over aligned 16-lane groups (one group = one batch's 16 blocks)
    #pragma unroll
    for (int off = 8; off > 0; off >>= 1) {
        x0 = fmaxf(x0, __shfl_xor(x0, off));
        x1 = fmaxf(x1, __shfl_xor(x1, off));
    }
    if ((t & 15) == 0) {
        bmax[t >> 4] = x0;
        bmax[(t >> 4) + 16] = x1;
    }
    __syncthreads();
    if (t < 64) {
        float x = (t < 32) ? bmax[t] : 0.f;
        #pragma unroll
        for (int off = 16; off > 0; off >>= 1)
            x += __shfl_down(x, off);
        if (t == 0) out[0] = x;
    }
}

extern "C" void kernel_launch(void* const* d_in, const int* in_sizes, int n_in,
                              void* d_out, int out_size, void* d_ws, size_t ws_size,
                              hipStream_t stream) {
    const float* gt = (const float*)d_in[0];
    const float* sp = (const float*)d_in[1];
    float* blocks = (float*)d_ws;
    unsigned* counter = (unsigned*)((char*)d_ws + 2048);
    float* out = (float*)d_out;

    hipMemsetAsync(d_ws, 0, 2048 + sizeof(unsigned), stream);

    lap_block_sum_kernel<<<NWG, 256, 0, stream>>>(gt, sp, blocks, counter, out);
}

// Round 10
// 45.347 us; speedup vs baseline: 1.4423x; 1.4423x over previous
//
#include <hip/hip_runtime.h>

#define HH 512
#define WW 512
#define CC 3
#define WGB 8                  // 64-row bands per plane
#define NWG (WGB * CC * 32)    // 768
#define NXCD 8

// d_ws layout: float blocks[32][4][4] (2048 B), unsigned counter @2048

__global__ __launch_bounds__(256) void lap_block_sum_kernel(
    const float* __restrict__ gt, const float* __restrict__ sp,
    float* __restrict__ blocks, unsigned* __restrict__ counter,
    float* __restrict__ out)
{
    __shared__ float ldsr[16][WW];   // P1 boundaries in slots 0-7, P2 in 8-15
    __shared__ float red[4][4];
    __shared__ int lastFlag;
    __shared__ float bmax[32];

    const int orig = blockIdx.x;
    const int lin  = (orig & (NXCD - 1)) * (NWG / NXCD) + (orig >> 3);
    const int wgband = lin & (WGB - 1);
    const int plane  = lin >> 3;          // = b*CC + c
    const int c = plane % CC;

    const int t = threadIdx.x;
    const int wv = t >> 6, lane = t & 63;

    const size_t poff = (size_t)plane * (size_t)(HH * WW);
    const float* __restrict__ gtp = gt + poff;
    const float* __restrict__ spp = sp + poff;

    const int start = wgband * 64;
    const int h1 = start + wv * 8;        // pass-1 rows [h1, h1+8)
    const int h2 = start + 32 + wv * 8;   // pass-2 rows [h2, h2+8)
    const int colA = 4 * lane;
    const int colB = 256 + 4 * lane;

#define LOADDIFF(HS, DA, DB) do {                                   \
    const float* gr_ = gtp + (size_t)(HS) * WW;                     \
    const float* sr_ = spp + (size_t)(HS) * WW;                     \
    float4 ga_ = *(const float4*)(gr_ + colA);                      \
    float4 gb_ = *(const float4*)(gr_ + colB);                      \
    float4 sa_ = *(const float4*)(sr_ + colA);                      \
    float4 sb_ = *(const float4*)(sr_ + colB);                      \
    DA[0]=ga_.x-sa_.x; DA[1]=ga_.y-sa_.y;                           \
    DA[2]=ga_.z-sa_.z; DA[3]=ga_.w-sa_.w;                           \
    DB[0]=gb_.x-sb_.x; DB[1]=gb_.y-sb_.y;                           \
    DB[2]=gb_.z-sb_.z; DB[3]=gb_.w-sb_.w;                           \
} while (0)

    // ---- pass 1: halo + 8 rows, publish boundaries ----
    float hA[4], hB[4];   // wv0: row start-1 (reflect); wv3: row start+32
    if (wv == 0 || wv == 3) {
        int hs = (wv == 0) ? (start == 0 ? 1 : start - 1) : (start + 32);
        LOADDIFF(hs, hA, hB);
    }

    float d1A[8][4], d1B[8][4];
    #pragma unroll
    for (int r = 0; r < 8; ++r) LOADDIFF(h1 + r, d1A[r], d1B[r]);

    *(float4*)&ldsr[2*wv  ][colA] = *(const float4*)&d1A[0][0];
    *(float4*)&ldsr[2*wv  ][colB] = *(const float4*)&d1B[0][0];
    *(float4*)&ldsr[2*wv+1][colA] = *(const float4*)&d1A[7][0];
    *(float4*)&ldsr[2*wv+1][colB] = *(const float4*)&d1B[7][0];
    __syncthreads();   // barrier 1 (drains P1 loads)

    float p1A[4], p1B[4], n1A[4], n1B[4];
    if (wv == 0) {
        #pragma unroll
        for (int i = 0; i < 4; ++i) { p1A[i]=hA[i]; p1B[i]=hB[i]; }
    } else {
        float4 a = *(const float4*)&ldsr[2*wv-1][colA];
        float4 q = *(const float4*)&ldsr[2*wv-1][colB];
        p1A[0]=a.x;p1A[1]=a.y;p1A[2]=a.z;p1A[3]=a.w;
        p1B[0]=q.x;p1B[1]=q.y;p1B[2]=q.z;p1B[3]=q.w;
    }
    if (wv == 3) {
        #pragma unroll
        for (int i = 0; i < 4; ++i) { n1A[i]=hA[i]; n1B[i]=hB[i]; }
    } else {
        float4 a = *(const float4*)&ldsr[2*wv+2][colA];
        float4 q = *(const float4*)&ldsr[2*wv+2][colB];
        n1A[0]=a.x;n1A[1]=a.y;n1A[2]=a.z;n1A[3]=a.w;
        n1B[0]=q.x;n1B[1]=q.y;n1B[2]=q.z;n1B[3]=q.w;
    }

    // ---- stencil machinery ----
    const int hzA0 = colA/384, hzA1 = (512+colA)/384, hzA2 = (1024+colA)/384;
    const int hzB0 = colB/384, hzB1 = (512+colB)/384, hzB2 = (1024+colB)/384;
    const int lm1 = (lane + 63) & 63, lp1 = (lane + 1) & 63;

    float acc0=0.f, acc1=0.f, acc2=0.f, acc3=0.f;

#define ROWSTEP(DDA,DDB,TA,TB,RM,BA,BB) do {                            \
    float csA0 = TA[0]+DDA[RM][0]+BA[0];                                \
    float csA1 = TA[1]+DDA[RM][1]+BA[1];                                \
    float csA2 = TA[2]+DDA[RM][2]+BA[2];                                \
    float csA3 = TA[3]+DDA[RM][3]+BA[3];                                \
    float csB0 = TB[0]+DDB[RM][0]+BB[0];                                \
    float csB1 = TB[1]+DDB[RM][1]+BB[1];                                \
    float csB2 = TB[2]+DDB[RM][2]+BB[2];                                \
    float csB3 = TB[3]+DDB[RM][3]+BB[3];                                \
    float sA3m = __shfl(csA3, lm1), sA0p = __shfl(csA0, lp1);           \
    float sB3m = __shfl(csB3, lm1), sB0p = __shfl(csB0, lp1);           \
    float xR = __shfl(csB0, 0),     xL = __shfl(csA3, 63);              \
    float lA = (lane==0)  ? csA1 : sA3m;  /* col -1 -> reflect col 1 */ \
    float rA = (lane==63) ? xR   : sA0p;  /* col 256 */                 \
    float lB = (lane==0)  ? xL   : sB3m;  /* col 255 */                 \
    float rB = (lane==63) ? csB2 : sB0p;  /* col 512 -> reflect 510 */  \
    float sA = fabsf(lA  +csA0+csA1 - 9.f*DDA[RM][0])                   \
             + fabsf(csA0+csA1+csA2 - 9.f*DDA[RM][1])                   \
             + fabsf(csA1+csA2+csA3 - 9.f*DDA[RM][2])                   \
             + fabsf(csA2+csA3+rA   - 9.f*DDA[RM][3]);                  \
    float sB = fabsf(lB  +csB0+csB1 - 9.f*DDB[RM][0])                   \
             + fabsf(csB0+csB1+csB2 - 9.f*DDB[RM][1])                   \
             + fabsf(csB1+csB2+csB3 - 9.f*DDB[RM][2])                   \
             + fabsf(csB2+csB3+rB   - 9.f*DDB[RM][3]);                  \
    int hzA = (m==0)?hzA0:((m==1)?hzA1:hzA2);                           \
    int hzB = (m==0)?hzB0:((m==1)?hzB1:hzB2);                           \
    acc0 += ((hzA==0)?sA:0.f) + ((hzB==0)?sB:0.f);                      \
    acc1 += ((hzA==1)?sA:0.f) + ((hzB==1)?sB:0.f);                      \
    acc2 += ((hzA==2)?sA:0.f) + ((hzB==2)?sB:0.f);                      \
    acc3 += ((hzA==3)?sA:0.f) + ((hzB==3)?sB:0.f);                      \
    m = (m==2)?0:(m+1);                                                 \
} while(0)

    // ---- pass-2 loads interleaved into pass-1 compute ----
    float d2A[8][4], d2B[8][4];
    float h3A[4], h3B[4];   // P2 bottom halo (wv3): row start+64, reflect at 512
    if (wv == 3) {
        int hs = (start + 64 > HH - 1) ? HH - 2 : start + 64;
        LOADDIFF(hs, h3A, h3B);
    }

    int m = (c * HH + h1) % 3;

    LOADDIFF(h2 + 0, d2A[0], d2B[0]);
    ROWSTEP(d1A,d1B, p1A,   p1B,   0, d1A[1], d1B[1]);
    LOADDIFF(h2 + 1, d2A[1], d2B[1]);
    ROWSTEP(d1A,d1B, d1A[0],d1B[0], 1, d1A[2], d1B[2]);
    LOADDIFF(h2 + 2, d2A[2], d2B[2]);
    ROWSTEP(d1A,d1B, d1A[1],d1B[1], 2, d1A[3], d1B[3]);
    LOADDIFF(h2 + 3, d2A[3], d2B[3]);
    ROWSTEP(d1A,d1B, d1A[2],d1B[2], 3, d1A[4], d1B[4]);
    LOADDIFF(h2 + 4, d2A[4], d2B[4]);
    ROWSTEP(d1A,d1B, d1A[3],d1B[3], 4, d1A[5], d1B[5]);
    LOADDIFF(h2 + 5, d2A[5], d2B[5]);
    ROWSTEP(d1A,d1B, d1A[4],d1B[4], 5, d1A[6], d1B[6]);
    LOADDIFF(h2 + 6, d2A[6], d2B[6]);
    ROWSTEP(d1A,d1B, d1A[5],d1B[5], 6, d1A[7], d1B[7]);
    LOADDIFF(h2 + 7, d2A[7], d2B[7]);
    ROWSTEP(d1A,d1B, d1A[6],d1B[6], 7, n1A,    n1B);

    // ---- pass 2: publish boundaries, compute ----
    *(float4*)&ldsr[8+2*wv  ][colA] = *(const float4*)&d2A[0][0];
    *(float4*)&ldsr[8+2*wv  ][colB] = *(const float4*)&d2B[0][0];
    *(float4*)&ldsr[8+2*wv+1][colA] = *(const float4*)&d2A[7][0];
    *(float4*)&ldsr[8+2*wv+1][colB] = *(const float4*)&d2B[7][0];
    __syncthreads();   // barrier 2 (P2 loads long since landed)

    float p2A[4], p2B[4], n2A[4], n2B[4];
    {
        // wv0's prev row (start+31) is P1 wv3's bottom boundary = slot 7
        const int ps = (wv == 0) ? 7 : (8 + 2*wv - 1);
        float4 a = *(const float4*)&ldsr[ps][colA];
        float4 q = *(const float4*)&ldsr[ps][colB];
        p2A[0]=a.x;p2A[1]=a.y;p2A[2]=a.z;p2A[3]=a.w;
        p2B[0]=q.x;p2B[1]=q.y;p2B[2]=q.z;p2B[3]=q.w;
    }
    if (wv == 3) {
        #pragma unroll
        for (int i = 0; i < 4; ++i) { n2A[i]=h3A[i]; n2B[i]=h3B[i]; }
    } else {
        float4 a = *(const float4*)&ldsr[8+2*wv+2][colA];
        float4 q = *(const float4*)&ldsr[8+2*wv+2][colB];
        n2A[0]=a.x;n2A[1]=a.y;n2A[2]=a.z;n2A[3]=a.w;
        n2B[0]=q.x;n2B[1]=q.y;n2B[2]=q.z;n2B[3]=q.w;
    }

    m = (c * HH + h2) % 3;
    ROWSTEP(d2A,d2B, p2A,   p2B,   0, d2A[1], d2B[1]);
    ROWSTEP(d2A,d2B, d2A[0],d2B[0], 1, d2A[2], d2B[2]);
    ROWSTEP(d2A,d2B, d2A[1],d2B[1], 2, d2A[3], d2B[3]);
    ROWSTEP(d2A,d2B, d2A[2],d2B[2], 3, d2A[4], d2B[4]);
    ROWSTEP(d2A,d2B, d2A[3],d2B[3], 4, d2A[5], d2B[5]);
    ROWSTEP(d2A,d2B, d2A[4],d2B[4], 5, d2A[6], d2B[6]);
    ROWSTEP(d2A,d2B, d2A[5],d2B[5], 6, d2A[7], d2B[7]);
    ROWSTEP(d2A,d2B, d2A[6],d2B[6], 7, n2A,    n2B);
#undef ROWSTEP
#undef LOADDIFF

    // ---- reduce across both passes ----
    #pragma unroll
    for (int off = 32; off > 0; off >>= 1) {
        acc0 += __shfl_xor(acc0, off);
        acc1 += __shfl_xor(acc1, off);
        acc2 += __shfl_xor(acc2, off);
        acc3 += __shfl_xor(acc3, off);
    }
    if (lane == 0) {
        red[wv][0] = acc0 * 0.0625f; red[wv][1] = acc1 * 0.0625f;
        red[wv][2] = acc2 * 0.0625f; red[wv][3] = acc3 * 0.0625f;
    }
    __syncthreads();

    const int v = (c * HH + start) / 384;   // uniform over the 64-row band
    const int b = plane / CC;
    if (t < 4) {
        float r = red[0][t] + red[1][t] + red[2][t] + red[3][t];
        atomicAdd(&blocks[(b * 4 + v) * 4 + t], r);   // device-coherent RMW (relaxed)
    }
    __syncthreads();   // compiler emits s_waitcnt vmcnt(0) before s_barrier:
                       // our atomicAdds have COMPLETED at the coherence point.

    // ---- last workgroup finalizes ----
    // Visibility argument (no fences needed): every cross-WG datum flows through
    // device-scope atomic RMWs performed at the coherence point; each WG bumps
    // the counter only after its RMWs completed (vmcnt drained by the barrier
    // above). RELAXED avoids the agent-scope ACQ_REL cache-maintenance
    // (buffer_wbl2/inv per WG) that cost ~30 us in round 9.
    if (t == 0) {
        unsigned old = __hip_atomic_fetch_add(counter, 1u, __ATOMIC_RELAXED,
                                              __HIP_MEMORY_SCOPE_AGENT);
        lastFlag = (old == (unsigned)(NWG - 1));
    }
    __syncthreads();
    if (!lastFlag) return;

    // 512 entries = blocks[b][v][hz]; thread t handles entries t and t+256
    float x0 = __hip_atomic_load(&blocks[t], __ATOMIC_RELAXED,
                                 __HIP_MEMORY_SCOPE_AGENT);
    float x1 = __hip_atomic_load(&blocks[t + 256], __ATOMIC_RELAXED,
                                 __HIP_MEMORY_SCOPE_AGENT);
    // max over aligned 16-lane groups (one group = one batch's 16 blocks)
    #pragma unroll
    for (int off = 8; off > 0; off >>= 1) {
        x0 = fmaxf(x0, __shfl_xor(x0, off));
        x1 = fmaxf(x1, __shfl_xor(x1, off));
    }
    if ((t & 15) == 0) {
        bmax[t >> 4] = x0;
        bmax[(t >> 4) + 16] = x1;
    }
    __syncthreads();
    if (t < 64) {
        float x = (t < 32) ? bmax[t] : 0.f;
        #pragma unroll
        for (int off = 16; off > 0; off >>= 1)
            x += __shfl_down(x, off);
        if (t == 0) out[0] = x;
    }
}

extern "C" void kernel_launch(void* const* d_in, const int* in_sizes, int n_in,
                              void* d_out, int out_size, void* d_ws, size_t ws_size,
                              hipStream_t stream) {
    const float* gt = (const float*)d_in[0];
    const float* sp = (const float*)d_in[1];
    float* blocks = (float*)d_ws;
    unsigned* counter = (unsigned*)((char*)d_ws + 2048);
    float* out = (float*)d_out;

    hipMemsetAsync(d_ws, 0, 2048 + sizeof(unsigned), stream);

    lap_block_sum_kernel<<<NWG, 256, 0, stream>>>(gt, sp, blocks, counter, out);
}

// Round 11
// 40.570 us; speedup vs baseline: 1.6121x; 1.1178x over previous
//
#include <hip/hip_runtime.h>

#define HH 512
#define WW 512
#define CC 3
#define WGB 8                  // 64-row bands per plane
#define NWG (WGB * CC * 32)    // 768
#define NXCD 8

// d_ws layout: float partial[NWG][4]

__global__ __launch_bounds__(256) void lap_block_sum_kernel(
    const float* __restrict__ gt, const float* __restrict__ sp,
    float* __restrict__ partial)
{
    __shared__ float ldsr[16][WW];   // P1 boundaries in slots 0-7, P2 in 8-15
    __shared__ float red[4][4];

    const int orig = blockIdx.x;
    const int lin  = (orig & (NXCD - 1)) * (NWG / NXCD) + (orig >> 3);
    const int wgband = lin & (WGB - 1);
    const int plane  = lin >> 3;          // = b*CC + c
    const int c = plane % CC;

    const int t = threadIdx.x;
    const int wv = t >> 6, lane = t & 63;

    const size_t poff = (size_t)plane * (size_t)(HH * WW);
    const float* __restrict__ gtp = gt + poff;
    const float* __restrict__ spp = sp + poff;

    const int start = wgband * 64;
    const int h1 = start + wv * 8;        // pass-1 rows [h1, h1+8)
    const int h2 = start + 32 + wv * 8;   // pass-2 rows [h2, h2+8)
    const int colA = 4 * lane;
    const int colB = 256 + 4 * lane;

#define LOADDIFF(HS, DA, DB) do {                                   \
    const float* gr_ = gtp + (size_t)(HS) * WW;                     \
    const float* sr_ = spp + (size_t)(HS) * WW;                     \
    float4 ga_ = *(const float4*)(gr_ + colA);                      \
    float4 gb_ = *(const float4*)(gr_ + colB);                      \
    float4 sa_ = *(const float4*)(sr_ + colA);                      \
    float4 sb_ = *(const float4*)(sr_ + colB);                      \
    DA[0]=ga_.x-sa_.x; DA[1]=ga_.y-sa_.y;                           \
    DA[2]=ga_.z-sa_.z; DA[3]=ga_.w-sa_.w;                           \
    DB[0]=gb_.x-sb_.x; DB[1]=gb_.y-sb_.y;                           \
    DB[2]=gb_.z-sb_.z; DB[3]=gb_.w-sb_.w;                           \
} while (0)

    // ---- pass 1: halo + 8 rows, publish boundaries ----
    float hA[4], hB[4];   // wv0: row start-1 (reflect); wv3: row start+32
    if (wv == 0 || wv == 3) {
        int hs = (wv == 0) ? (start == 0 ? 1 : start - 1) : (start + 32);
        LOADDIFF(hs, hA, hB);
    }

    float d1A[8][4], d1B[8][4];
    #pragma unroll
    for (int r = 0; r < 8; ++r) LOADDIFF(h1 + r, d1A[r], d1B[r]);

    *(float4*)&ldsr[2*wv  ][colA] = *(const float4*)&d1A[0][0];
    *(float4*)&ldsr[2*wv  ][colB] = *(const float4*)&d1B[0][0];
    *(float4*)&ldsr[2*wv+1][colA] = *(const float4*)&d1A[7][0];
    *(float4*)&ldsr[2*wv+1][colB] = *(const float4*)&d1B[7][0];
    __syncthreads();   // barrier 1 (drains P1 loads)

    float p1A[4], p1B[4], n1A[4], n1B[4];
    if (wv == 0) {
        #pragma unroll
        for (int i = 0; i < 4; ++i) { p1A[i]=hA[i]; p1B[i]=hB[i]; }
    } else {
        float4 a = *(const float4*)&ldsr[2*wv-1][colA];
        float4 q = *(const float4*)&ldsr[2*wv-1][colB];
        p1A[0]=a.x;p1A[1]=a.y;p1A[2]=a.z;p1A[3]=a.w;
        p1B[0]=q.x;p1B[1]=q.y;p1B[2]=q.z;p1B[3]=q.w;
    }
    if (wv == 3) {
        #pragma unroll
        for (int i = 0; i < 4; ++i) { n1A[i]=hA[i]; n1B[i]=hB[i]; }
    } else {
        float4 a = *(const float4*)&ldsr[2*wv+2][colA];
        float4 q = *(const float4*)&ldsr[2*wv+2][colB];
        n1A[0]=a.x;n1A[1]=a.y;n1A[2]=a.z;n1A[3]=a.w;
        n1B[0]=q.x;n1B[1]=q.y;n1B[2]=q.z;n1B[3]=q.w;
    }

    // ---- stencil machinery ----
    const int hzA0 = colA/384, hzA1 = (512+colA)/384, hzA2 = (1024+colA)/384;
    const int hzB0 = colB/384, hzB1 = (512+colB)/384, hzB2 = (1024+colB)/384;
    const int lm1 = (lane + 63) & 63, lp1 = (lane + 1) & 63;

    float acc0=0.f, acc1=0.f, acc2=0.f, acc3=0.f;

#define ROWSTEP(DDA,DDB,TA,TB,RM,BA,BB) do {                            \
    float csA0 = TA[0]+DDA[RM][0]+BA[0];                                \
    float csA1 = TA[1]+DDA[RM][1]+BA[1];                                \
    float csA2 = TA[2]+DDA[RM][2]+BA[2];                                \
    float csA3 = TA[3]+DDA[RM][3]+BA[3];                                \
    float csB0 = TB[0]+DDB[RM][0]+BB[0];                                \
    float csB1 = TB[1]+DDB[RM][1]+BB[1];                                \
    float csB2 = TB[2]+DDB[RM][2]+BB[2];                                \
    float csB3 = TB[3]+DDB[RM][3]+BB[3];                                \
    float sA3m = __shfl(csA3, lm1), sA0p = __shfl(csA0, lp1);           \
    float sB3m = __shfl(csB3, lm1), sB0p = __shfl(csB0, lp1);           \
    float xR = __shfl(csB0, 0),     xL = __shfl(csA3, 63);              \
    float lA = (lane==0)  ? csA1 : sA3m;  /* col -1 -> reflect col 1 */ \
    float rA = (lane==63) ? xR   : sA0p;  /* col 256 */                 \
    float lB = (lane==0)  ? xL   : sB3m;  /* col 255 */                 \
    float rB = (lane==63) ? csB2 : sB0p;  /* col 512 -> reflect 510 */  \
    float sA = fabsf(lA  +csA0+csA1 - 9.f*DDA[RM][0])                   \
             + fabsf(csA0+csA1+csA2 - 9.f*DDA[RM][1])                   \
             + fabsf(csA1+csA2+csA3 - 9.f*DDA[RM][2])                   \
             + fabsf(csA2+csA3+rA   - 9.f*DDA[RM][3]);                  \
    float sB = fabsf(lB  +csB0+csB1 - 9.f*DDB[RM][0])                   \
             + fabsf(csB0+csB1+csB2 - 9.f*DDB[RM][1])                   \
             + fabsf(csB1+csB2+csB3 - 9.f*DDB[RM][2])                   \
             + fabsf(csB2+csB3+rB   - 9.f*DDB[RM][3]);                  \
    int hzA = (m==0)?hzA0:((m==1)?hzA1:hzA2);                           \
    int hzB = (m==0)?hzB0:((m==1)?hzB1:hzB2);                           \
    acc0 += ((hzA==0)?sA:0.f) + ((hzB==0)?sB:0.f);                      \
    acc1 += ((hzA==1)?sA:0.f) + ((hzB==1)?sB:0.f);                      \
    acc2 += ((hzA==2)?sA:0.f) + ((hzB==2)?sB:0.f);                      \
    acc3 += ((hzA==3)?sA:0.f) + ((hzB==3)?sB:0.f);                      \
    m = (m==2)?0:(m+1);                                                 \
} while(0)

    // ---- pass-2 loads interleaved into pass-1 compute ----
    float d2A[8][4], d2B[8][4];
    float h3A[4], h3B[4];   // P2 bottom halo (wv3): row start+64, reflect at 512
    if (wv == 3) {
        int hs = (start + 64 > HH - 1) ? HH - 2 : start + 64;
        LOADDIFF(hs, h3A, h3B);
    }

    int m = (c * HH + h1) % 3;

    LOADDIFF(h2 + 0, d2A[0], d2B[0]);
    ROWSTEP(d1A,d1B, p1A,   p1B,   0, d1A[1], d1B[1]);
    LOADDIFF(h2 + 1, d2A[1], d2B[1]);
    ROWSTEP(d1A,d1B, d1A[0],d1B[0], 1, d1A[2], d1B[2]);
    LOADDIFF(h2 + 2, d2A[2], d2B[2]);
    ROWSTEP(d1A,d1B, d1A[1],d1B[1], 2, d1A[3], d1B[3]);
    LOADDIFF(h2 + 3, d2A[3], d2B[3]);
    ROWSTEP(d1A,d1B, d1A[2],d1B[2], 3, d1A[4], d1B[4]);
    LOADDIFF(h2 + 4, d2A[4], d2B[4]);
    ROWSTEP(d1A,d1B, d1A[3],d1B[3], 4, d1A[5], d1B[5]);
    LOADDIFF(h2 + 5, d2A[5], d2B[5]);
    ROWSTEP(d1A,d1B, d1A[4],d1B[4], 5, d1A[6], d1B[6]);
    LOADDIFF(h2 + 6, d2A[6], d2B[6]);
    ROWSTEP(d1A,d1B, d1A[5],d1B[5], 6, d1A[7], d1B[7]);
    LOADDIFF(h2 + 7, d2A[7], d2B[7]);
    ROWSTEP(d1A,d1B, d1A[6],d1B[6], 7, n1A,    n1B);

    // ---- pass 2: publish boundaries, compute ----
    *(float4*)&ldsr[8+2*wv  ][colA] = *(const float4*)&d2A[0][0];
    *(float4*)&ldsr[8+2*wv  ][colB] = *(const float4*)&d2B[0][0];
    *(float4*)&ldsr[8+2*wv+1][colA] = *(const float4*)&d2A[7][0];
    *(float4*)&ldsr[8+2*wv+1][colB] = *(const float4*)&d2B[7][0];
    __syncthreads();   // barrier 2 (P2 loads long since landed)

    float p2A[4], p2B[4], n2A[4], n2B[4];
    {
        // wv0's prev row (start+31) is P1 wv3's bottom boundary = slot 7
        const int ps = (wv == 0) ? 7 : (8 + 2*wv - 1);
        float4 a = *(const float4*)&ldsr[ps][colA];
        float4 q = *(const float4*)&ldsr[ps][colB];
        p2A[0]=a.x;p2A[1]=a.y;p2A[2]=a.z;p2A[3]=a.w;
        p2B[0]=q.x;p2B[1]=q.y;p2B[2]=q.z;p2B[3]=q.w;
    }
    if (wv == 3) {
        #pragma unroll
        for (int i = 0; i < 4; ++i) { n2A[i]=h3A[i]; n2B[i]=h3B[i]; }
    } else {
        float4 a = *(const float4*)&ldsr[8+2*wv+2][colA];
        float4 q = *(const float4*)&ldsr[8+2*wv+2][colB];
        n2A[0]=a.x;n2A[1]=a.y;n2A[2]=a.z;n2A[3]=a.w;
        n2B[0]=q.x;n2B[1]=q.y;n2B[2]=q.z;n2B[3]=q.w;
    }

    m = (c * HH + h2) % 3;
    ROWSTEP(d2A,d2B, p2A,   p2B,   0, d2A[1], d2B[1]);
    ROWSTEP(d2A,d2B, d2A[0],d2B[0], 1, d2A[2], d2B[2]);
    ROWSTEP(d2A,d2B, d2A[1],d2B[1], 2, d2A[3], d2B[3]);
    ROWSTEP(d2A,d2B, d2A[2],d2B[2], 3, d2A[4], d2B[4]);
    ROWSTEP(d2A,d2B, d2A[3],d2B[3], 4, d2A[5], d2B[5]);
    ROWSTEP(d2A,d2B, d2A[4],d2B[4], 5, d2A[6], d2B[6]);
    ROWSTEP(d2A,d2B, d2A[5],d2B[5], 6, d2A[7], d2B[7]);
    ROWSTEP(d2A,d2B, d2A[6],d2B[6], 7, n2A,    n2B);
#undef ROWSTEP
#undef LOADDIFF

    // ---- reduce across both passes ----
    #pragma unroll
    for (int off = 32; off > 0; off >>= 1) {
        acc0 += __shfl_xor(acc0, off);
        acc1 += __shfl_xor(acc1, off);
        acc2 += __shfl_xor(acc2, off);
        acc3 += __shfl_xor(acc3, off);
    }
    if (lane == 0) {
        red[wv][0] = acc0 * 0.0625f; red[wv][1] = acc1 * 0.0625f;
        red[wv][2] = acc2 * 0.0625f; red[wv][3] = acc3 * 0.0625f;
    }
    __syncthreads();
    if (t < 4) {
        partial[lin * 4 + t] = red[0][t] + red[1][t] + red[2][t] + red[3][t];
    }
}

__global__ void finalize_kernel(const float* __restrict__ partial,
                                float* __restrict__ out, int B)
{
    __shared__ float bmax[32];
    const int t = threadIdx.x;                  // 512 threads
    const int b = t >> 4, v = (t >> 2) & 3, hz = t & 3;
    float s = 0.f;
    if (b < B) {
        #pragma unroll
        for (int c = 0; c < CC; ++c) {
            #pragma unroll
            for (int band = 0; band < WGB; ++band) {
                if ((c * HH + band * 64) / 384 == v)
                    s += partial[((b * CC + c) * WGB + band) * 4 + hz];
            }
        }
    }
    #pragma unroll
    for (int off = 8; off > 0; off >>= 1)
        s = fmaxf(s, __shfl_xor(s, off));
    if ((t & 15) == 0) bmax[b] = (b < B) ? s : 0.f;
    __syncthreads();
    if (t < 64) {
        float x = (t < 32) ? bmax[t] : 0.f;
        #pragma unroll
        for (int off = 16; off > 0; off >>= 1)
            x += __shfl_down(x, off);
        if (t == 0) out[0] = x;
    }
}

extern "C" void kernel_launch(void* const* d_in, const int* in_sizes, int n_in,
                              void* d_out, int out_size, void* d_ws, size_t ws_size,
                              hipStream_t stream) {
    const float* gt = (const float*)d_in[0];
    const float* sp = (const float*)d_in[1];
    float* partial = (float*)d_ws;
    float* out = (float*)d_out;

    const int B = in_sizes[0] / (CC * HH * WW);  // 32

    lap_block_sum_kernel<<<NWG, 256, 0, stream>>>(gt, sp, partial);

    finalize_kernel<<<1, 512, 0, stream>>>(partial, out, B);
}